// Round 6
// baseline (250.587 us; speedup 1.0000x reference)
//
#include <hip/hip_runtime.h>

typedef __bf16 bf16;
typedef __attribute__((ext_vector_type(8))) __bf16 bf16x8;
typedef __attribute__((ext_vector_type(4))) float f32x4;
typedef __attribute__((ext_vector_type(16))) float f32x16;
typedef unsigned int u32;

#define MFMA16(a, b, c) __builtin_amdgcn_mfma_f32_16x16x32_bf16((a), (b), (c), 0, 0, 0)
#define MFMA32(a, b, c) __builtin_amdgcn_mfma_f32_32x32x16_bf16((a), (b), (c), 0, 0, 0)

// Problem constants
#define BB 2
#define SS 2048
#define EE 1024
#define HH 16
#define DD 64
#define MM (BB * SS)  // 4096
#define NT (SS / 64)  // 32 K-tiles

__device__ inline f32x4 zero4() {
    f32x4 z; z.x = 0.f; z.y = 0.f; z.z = 0.f; z.w = 0.f; return z;
}

// async global->LDS DMA, 16B per lane.  LDS dest = wave-uniform base + lane*16.
__device__ __forceinline__ void gload16(const bf16* g, bf16* l) {
    __builtin_amdgcn_global_load_lds(
        (const __attribute__((address_space(1))) u32*)(const void*)g,
        (__attribute__((address_space(3))) u32*)(void*)l,
        16, 0, 0);
}

__device__ __forceinline__ u32 pkbf(float a, float b) {
    union { __bf16 h; unsigned short s; } ua, ub;
    ua.h = (__bf16)a; ub.h = (__bf16)b;
    return (u32)ua.s | ((u32)ub.s << 16);
}

// ---------------------------------------------------------------------------
// Kernel 1: fused prep.
// ---------------------------------------------------------------------------
__global__ __launch_bounds__(256) void prep_kernel(
    const float* __restrict__ query, bf16* __restrict__ qc,
    const float* __restrict__ s0, const float* __restrict__ s1,
    const float* __restrict__ s2, const float* __restrict__ s3,
    bf16* __restrict__ d0, bf16* __restrict__ d1,
    bf16* __restrict__ d2, bf16* __restrict__ d3,
    const float* __restrict__ xi, const float* __restrict__ w1,
    const float* __restrict__ b1, const float* __restrict__ lng,
    const float* __restrict__ lnb, const float* __restrict__ w2,
    const float* __restrict__ b2, const float* __restrict__ gate,
    float* __restrict__ adapt) {
    __shared__ bf16 tile[64 * 72];
    const int bid = blockIdx.x;
    const int t = threadIdx.x;

    if (bid < 2048) {
        const int i = (bid * 256 + t) * 8;
        float4 a = *(const float4*)(query + i);
        float4 b = *(const float4*)(query + i + 4);
        bf16 tmp[8];
        tmp[0] = (bf16)a.x; tmp[1] = (bf16)a.y; tmp[2] = (bf16)a.z; tmp[3] = (bf16)a.w;
        tmp[4] = (bf16)b.x; tmp[5] = (bf16)b.y; tmp[6] = (bf16)b.z; tmp[7] = (bf16)b.w;
        *(uint4*)(qc + i) = *(uint4*)tmp;
    } else if (bid < 3072) {
        const int m = (bid - 2048) >> 8;
        const int idx0 = (bid - 2048) & 255;
        const float* W = (m == 0) ? s0 : (m == 1) ? s1 : (m == 2) ? s2 : s3;
        bf16* Wt = (m == 0) ? d0 : (m == 1) ? d1 : (m == 2) ? d2 : d3;
        const int k0 = (idx0 >> 4) * 64, n0 = (idx0 & 15) * 64;
#pragma unroll
        for (int i = 0; i < 2; ++i) {
            int idx = i * 256 + t;
            int r = idx >> 3, c = (idx & 7) * 8;
            float4 a = *(const float4*)(W + (k0 + r) * EE + n0 + c);
            float4 b = *(const float4*)(W + (k0 + r) * EE + n0 + c + 4);
            bf16 tmp[8];
            tmp[0] = (bf16)a.x; tmp[1] = (bf16)a.y; tmp[2] = (bf16)a.z; tmp[3] = (bf16)a.w;
            tmp[4] = (bf16)b.x; tmp[5] = (bf16)b.y; tmp[6] = (bf16)b.z; tmp[7] = (bf16)b.w;
            *(uint4*)(tile + r * 72 + c) = *(uint4*)tmp;
        }
        __syncthreads();
#pragma unroll
        for (int i = 0; i < 2; ++i) {
            int idx = i * 256 + t;
            int n = idx >> 3, kc = (idx & 7) * 8;
            bf16 tmp[8];
#pragma unroll
            for (int j = 0; j < 8; ++j) tmp[j] = tile[(kc + j) * 72 + n];
            *(uint4*)(Wt + (n0 + n) * EE + k0 + kc) = *(uint4*)tmp;
        }
    } else {
        const int b = bid - 3072;
        float* xs = (float*)tile;
        if (t < 64) {
            const float xiv = xi[b];
            float xv = 0.f;
            if (t < 32) xv = xiv * w1[t] + b1[t];
            float sm = xv;
            for (int off = 1; off < 32; off <<= 1) sm += __shfl_xor(sm, off);
            const float mu = sm * (1.f / 32.f);
            float dv = (t < 32) ? (xv - mu) : 0.f;
            float s2 = dv * dv;
            for (int off = 1; off < 32; off <<= 1) s2 += __shfl_xor(s2, off);
            const float var = s2 * (1.f / 32.f);
            if (t < 32) {
                float xn = (xv - mu) * rsqrtf(var + 1e-5f) * lng[t] + lnb[t];
                float ge = 0.5f * xn * (1.f + erff(xn * 0.70710678118654752f));
                xs[t] = ge;
            }
        }
        __syncthreads();
        if (t < 64) {
            float acc = b2[t];
            for (int j = 0; j < 32; ++j) acc += xs[j] * w2[j * DD + t];
            for (int h = 0; h < HH; ++h) {
                float sg = 1.f / (1.f + __expf(-gate[h]));
                adapt[(b * HH + h) * DD + t] = 1.f + sg * acc;
            }
        }
    }
}

// ---------------------------------------------------------------------------
// Kernel 2: QKV GEMM — 128x128 tile, BK=32, dbuf DMA, one barrier/iter.
// q-scale folds 0.125*log2(e) so attention uses bare v_exp_f32 (exp2).
// K and V^T outputs in PERMUTED TILE LAYOUT (R4):
//   idx = bh*131072 + kt*4096 + mf*2048 + c*512 + lane*8 + j
// Epilogue v2 (R5, verified): scaled results -> XOR-swizzled LDS tile ->
// 8 x dwordx4 stores/thread (was 64 scalar scattered stores; VMEM-issue
// bound).  bias/adapt hoisted to per-column FMA factors.
// ---------------------------------------------------------------------------
__global__ __launch_bounds__(256, 3) void gemm_qkv(
    const bf16* __restrict__ Aq, const bf16* __restrict__ Bqk,
    const bf16* __restrict__ Av,
    const float* __restrict__ bias, const float* __restrict__ bias2,
    const float* __restrict__ bias3, const float* __restrict__ adapt,
    bf16* __restrict__ outqk, bf16* __restrict__ outvt) {
    __shared__ bf16 sh[16384];  // main loop: As/Bs; epilogue: 128x128 tile
    bf16* As = sh;
    bf16* Bs = sh + 8192;

    const int t = threadIdx.x;
    const int w = t >> 6, lane = t & 63;
    const int mrow = lane & 15, quad = lane >> 4;
    const int wm = (w & 1) * 64, wn = (w >> 1) * 64;

    int md, bx, by;
    const bf16 *Ap, *Bp;
    int bid = blockIdx.x;
    if (bid < 512) { md = 5; bx = bid & 31; by = bid >> 5; Ap = Aq; Bp = Bqk; }
    else { md = 4; bid -= 512; bx = bid & 7; by = bid >> 3; Ap = Av; Bp = Aq; }
    const int m0 = bx * 128, n0 = by * 128;
    const int m2 = (md == 5) ? (by >> 3) : 0;  // 0=Q, 1=K (block-uniform)

    f32x4 acc[4][4];
#pragma unroll
    for (int i = 0; i < 4; ++i)
#pragma unroll
        for (int j = 0; j < 4; ++j) acc[i][j] = zero4();

    const int dr = lane >> 2;
    const int dcg = ((lane & 3) ^ (dr & 3)) * 8;
    const bf16* Ag = Ap + (size_t)(m0 + w * 16 + dr) * EE + dcg;
    const bf16* Bg = Bp + (size_t)(n0 + w * 16 + dr) * EE + dcg;
    bf16* Al = As + (w * 16) * 32;
    bf16* Bl = Bs + (w * 16) * 32;

    gload16(Ag, Al);
    gload16(Ag + 64 * EE, Al + 64 * 32);
    gload16(Bg, Bl);
    gload16(Bg + 64 * EE, Bl + 64 * 32);

    for (int kt = 0; kt < 32; ++kt) {
        __syncthreads();
        if (kt < 31) {
            const int kn = (kt + 1) * 32;
            const int nb = (kt + 1) & 1;
            gload16(Ag + kn, Al + nb * 4096);
            gload16(Ag + 64 * EE + kn, Al + nb * 4096 + 64 * 32);
            gload16(Bg + kn, Bl + nb * 4096);
            gload16(Bg + 64 * EE + kn, Bl + nb * 4096 + 64 * 32);
        }
        const bf16* Ab = As + (kt & 1) * 4096;
        const bf16* Bb = Bs + (kt & 1) * 4096;
        const int sw = (quad ^ (mrow & 3)) * 8;
        bf16x8 af[4], bfr[4];
#pragma unroll
        for (int i = 0; i < 4; ++i)
            af[i] = *(const bf16x8*)(Ab + (wm + i * 16 + mrow) * 32 + sw);
#pragma unroll
        for (int j = 0; j < 4; ++j)
            bfr[j] = *(const bf16x8*)(Bb + (wn + j * 16 + mrow) * 32 + sw);
#pragma unroll
        for (int i = 0; i < 4; ++i)
#pragma unroll
            for (int j = 0; j < 4; ++j)
                acc[i][j] = MFMA16(af[i], bfr[j], acc[i][j]);
    }

    // ---- epilogue v2: scale -> swizzled LDS -> vectorized stores ----
    __syncthreads();  // staging LDS now dead; safe to overwrite

    if (md == 5) {
        const int bq_ = m0 >> 11;
        float cmul[4], cadd[4];
#pragma unroll
        for (int j = 0; j < 4; ++j) {
            const int cl = (n0 & 1023) + wn + j * 16 + mrow;
            const int hh = cl >> 6, dd2 = cl & 63;
            const float ad = adapt[(bq_ * HH + hh) * DD + dd2];
            const float sc = m2 ? 1.f : 0.18033688011113811f;
            cmul[j] = ad * sc;
            cadd[j] = (m2 ? bias2[cl] : bias[cl]) * ad * sc;
        }
#pragma unroll
        for (int i = 0; i < 4; ++i)
#pragma unroll
            for (int j = 0; j < 4; ++j) {
                const int lcol = wn + j * 16 + mrow;
#pragma unroll
                for (int r = 0; r < 4; ++r) {
                    const int lrow = wm + i * 16 + quad * 4 + r;
                    const float v = acc[i][j][r] * cmul[j] + cadd[j];
                    *(bf16*)((char*)sh + lrow * 256 +
                             ((lcol * 2) ^ ((lrow & 15) << 4))) = (bf16)v;
                }
            }
    } else {
        float radd[16];
#pragma unroll
        for (int i = 0; i < 4; ++i)
#pragma unroll
            for (int r = 0; r < 4; ++r)
                radd[i * 4 + r] = bias3[m0 + wm + i * 16 + quad * 4 + r];
#pragma unroll
        for (int i = 0; i < 4; ++i)
#pragma unroll
            for (int j = 0; j < 4; ++j) {
                const int lcol = wn + j * 16 + mrow;
#pragma unroll
                for (int r = 0; r < 4; ++r) {
                    const int lrow = wm + i * 16 + quad * 4 + r;
                    const float v = acc[i][j][r] + radd[i * 4 + r];
                    *(bf16*)((char*)sh + lrow * 256 +
                             ((lcol * 2) ^ ((lrow & 15) << 4))) = (bf16)v;
                }
            }
    }
    __syncthreads();

#pragma unroll
    for (int p = 0; p < 8; ++p) {
        const int lrow = p * 16 + (t >> 4);
        const int lcol0 = (t & 15) * 8;
        bf16x8 val = *(const bf16x8*)((const char*)sh + lrow * 256 +
                                      ((lcol0 * 2) ^ ((lrow & 15) << 4)));
        if (md == 5) {
            const int bq_ = m0 >> 11;
            const int s_ = (m0 + lrow) & (SS - 1);
            const int cl = (n0 & 1023) + lcol0;
            const int hh = cl >> 6, d0 = cl & 63;
            if (!m2) {
                *(bf16x8*)(outqk + ((size_t)(bq_ * HH + hh) * SS + s_) * DD + d0) = val;
            } else {
                const size_t base = (size_t)MM * EE + (size_t)(bq_ * HH + hh) * 131072;
                const int a2 = (s_ >> 6) * 4096 + ((s_ >> 5) & 1) * 2048 +
                               (d0 >> 4) * 512 +
                               ((s_ & 31) + ((d0 >> 3) & 1) * 32) * 8;
                *(bf16x8*)(outqk + base + a2) = val;
            }
        } else {
            const int rowv = m0 + lrow;
            const int hv = rowv >> 6, dv = rowv & 63;
            const int colv = n0 + lcol0;
            const int bv_ = colv >> 11, sv = colv & (SS - 1);
            const size_t base = (size_t)(bv_ * HH + hv) * 131072;
            const int a2 = (sv >> 6) * 4096 + (dv >> 5) * 2048 +
                           ((sv >> 4) & 3) * 512 +
                           ((dv & 31) + ((sv >> 3) & 1) * 32) * 8;
            *(bf16x8*)(outvt + base + a2) = val;
        }
    }
}

// ---------------------------------------------------------------------------
// Kernel 3: final GEMM (R5 epilogue v2, verified).
// ---------------------------------------------------------------------------
__global__ __launch_bounds__(256, 3) void gemm_o(
    const bf16* __restrict__ A, const bf16* __restrict__ Bt,
    const float* __restrict__ bias, float* __restrict__ outf) {
    __shared__ bf16 As[2 * 128 * 64];  // 32KB; epilogue reuses as 128x64 f32
    __shared__ bf16 Bs[2 * 64 * 64];

    const int t = threadIdx.x;
    const int w = t >> 6, lane = t & 63;
    const int mrow = lane & 15, quad = lane >> 4;
    const int m0 = blockIdx.x * 128, n0 = blockIdx.y * 64;

    f32x4 acc[2][4];
#pragma unroll
    for (int i = 0; i < 2; ++i)
#pragma unroll
        for (int j = 0; j < 4; ++j) acc[i][j] = zero4();

    const int grow = lane >> 3;
    const int gsw = ((lane & 7) ^ grow) * 8;
    const bf16* Ag = A + (size_t)(m0 + w * 32 + grow) * EE + gsw;
    const bf16* Bg = Bt + (size_t)(n0 + w * 16 + grow) * EE + gsw;
    bf16* Al = As + (w * 32) * 64;
    bf16* Bl = Bs + (w * 16) * 64;

#pragma unroll
    for (int i = 0; i < 4; ++i) gload16(Ag + i * 8 * EE, Al + i * 8 * 64);
#pragma unroll
    for (int i = 0; i < 2; ++i) gload16(Bg + i * 8 * EE, Bl + i * 8 * 64);

    for (int kt = 0; kt < 16; ++kt) {
        __syncthreads();
        if (kt < 15) {
            const int kn = (kt + 1) * 64;
            const int nb = (kt + 1) & 1;
#pragma unroll
            for (int i = 0; i < 4; ++i)
                gload16(Ag + i * 8 * EE + kn, Al + nb * 8192 + i * 8 * 64);
#pragma unroll
            for (int i = 0; i < 2; ++i)
                gload16(Bg + i * 8 * EE + kn, Bl + nb * 4096 + i * 8 * 64);
        }
        const bf16* Ab = As + (kt & 1) * 8192;
        const bf16* Bb = Bs + (kt & 1) * 4096;
#pragma unroll
        for (int ks = 0; ks < 2; ++ks) {
            const int cg = ks * 4 + quad;
            const int sw = (cg ^ (mrow & 7)) * 8;
            bf16x8 af[2], bfr[4];
#pragma unroll
            for (int mi = 0; mi < 2; ++mi)
                af[mi] = *(const bf16x8*)(Ab + (w * 32 + mi * 16 + mrow) * 64 + sw);
#pragma unroll
            for (int nj = 0; nj < 4; ++nj)
                bfr[nj] = *(const bf16x8*)(Bb + (nj * 16 + mrow) * 64 + sw);
#pragma unroll
            for (int mi = 0; mi < 2; ++mi)
#pragma unroll
                for (int nj = 0; nj < 4; ++nj)
                    acc[mi][nj] = MFMA16(af[mi], bfr[nj], acc[mi][nj]);
        }
    }

    // ---- epilogue v2 ----
    __syncthreads();  // staging LDS dead
    char* fs = (char*)As;  // 128 rows x 256B (64 f32), swizzled
    float cadd[4];
#pragma unroll
    for (int nj = 0; nj < 4; ++nj) cadd[nj] = bias[n0 + nj * 16 + mrow];
#pragma unroll
    for (int mi = 0; mi < 2; ++mi)
#pragma unroll
        for (int nj = 0; nj < 4; ++nj) {
            const int lcol = nj * 16 + mrow;
#pragma unroll
            for (int r = 0; r < 4; ++r) {
                const int lrow = w * 32 + mi * 16 + quad * 4 + r;
                *(float*)(fs + lrow * 256 + ((lcol * 4) ^ ((lrow & 15) << 4))) =
                    acc[mi][nj][r] + cadd[nj];
            }
        }
    __syncthreads();

#pragma unroll
    for (int p = 0; p < 8; ++p) {
        const int lrow = p * 16 + (t >> 4);
        const int lcol0 = (t & 15) * 4;
        float4 val = *(const float4*)(fs + lrow * 256 +
                                      ((lcol0 * 4) ^ ((lrow & 15) << 4)));
        *(float4*)(outf + (size_t)(m0 + lrow) * EE + n0 + lcol0) = val;
    }
}

// ---------------------------------------------------------------------------
// Kernel 4: flash attention — R6: SOFTWARE-PIPELINED one tile ahead.
// R5 post-mortem: occupancy is WORK-LIMITED (2048 waves total = 2/SIMD);
// MfmaUtil 26% even as any-SIMD-busy -> per-wave serial chain
// QK(t)->exp(t)->PV(t) is the limit.  Now iteration t computes QK(t+1)
// (into st_next, consumed next iter -> no wait) then softmax+PV of tile t
// (whose QK MFMAs retired an iteration ago).  Load order V-then-K makes
// compiler waits counted (vmcnt(8)/(16), never 0).  +32 VGPR for the 2nd
// st: free (waves/SIMD work-limited at 2; 256-VGPR cliff is the only risk).
// Dead ends: split-K (nondeterminism), K-tile 32/128, LDS staging (R1-R3
// lockstep invariance), grid reshaping (R2/R3: shape-invariant).
// ---------------------------------------------------------------------------
__device__ __forceinline__ void attn_softpv(
    f32x16 (&stc)[2], const bf16x8 (&vf)[8],
    f32x16 (&oacc)[2], float (&ls)[4], int h) {
    u32 P32[2][8];
#pragma unroll
    for (int mf = 0; mf < 2; ++mf)
#pragma unroll
        for (int rp = 0; rp < 8; ++rp) {
            float pa = __builtin_amdgcn_exp2f(stc[mf][2 * rp]);
            float pb = __builtin_amdgcn_exp2f(stc[mf][2 * rp + 1]);
            ls[rp & 3] += pa + pb;
            P32[mf][rp] = pkbf(pa, pb);
        }
#pragma unroll
    for (int c = 0; c < 4; ++c) {
        const int mfs = c >> 1;
        const int ro = (c & 1) * 4;
        union { u32 u[4]; bf16x8 v; } pb;
        {
            u32 vA0 = P32[mfs][ro + 0], vA1 = P32[mfs][ro + 1];
            u32 vB0 = P32[mfs][ro + 2], vB1 = P32[mfs][ro + 3];
            u32 prep0 = h ? vA0 : vB0;
            u32 prep1 = h ? vA1 : vB1;
            u32 sh0 = __shfl_xor(prep0, 32);
            u32 sh1 = __shfl_xor(prep1, 32);
            pb.u[0] = h ? sh0 : vA0;
            pb.u[1] = h ? sh1 : vA1;
            pb.u[2] = h ? vB0 : sh0;
            pb.u[3] = h ? vB1 : sh1;
        }
        __builtin_amdgcn_s_setprio(1);
#pragma unroll
        for (int mf = 0; mf < 2; ++mf)
            oacc[mf] = MFMA32(vf[mf * 4 + c], pb.v, oacc[mf]);
        __builtin_amdgcn_s_setprio(0);
    }
}

// One pipelined step for tile t: issue V(t) + K(t+2) loads, QK(t+1) -> stn,
// softmax+PV(t) from stc.  Kn holds K(t+1); Kn2 (holding dead K(t)) receives
// K(t+2).  Static A/B alternation at the call sites (rule #20).
__device__ __forceinline__ void attn_pipe(
    int t, const bf16* kbase, const bf16* vbase, const bf16x8 (&qf)[4],
    f32x16 (&stc)[2], f32x16 (&stn)[2],
    bf16x8 (&Kn)[8], bf16x8 (&Kn2)[8],
    f32x16 (&oacc)[2], float (&ls)[4], int h) {
    // V(t) loads FIRST (waited at PV: vmcnt(8) -> K loads stay in flight)
    bf16x8 vf[8];
#pragma unroll
    for (int mf = 0; mf < 2; ++mf)
#pragma unroll
        for (int c = 0; c < 4; ++c)
            vf[mf * 4 + c] = *(const bf16x8*)(vbase + t * 4096 + mf * 2048 + c * 512);

    // K(t+2) prefetch (clamped at the tail; redundant load is harmless)
    const int tk = (t + 2 < NT) ? t + 2 : NT - 1;
#pragma unroll
    for (int mf = 0; mf < 2; ++mf)
#pragma unroll
        for (int c = 0; c < 4; ++c)
            Kn2[mf * 4 + c] = *(const bf16x8*)(kbase + tk * 4096 + mf * 2048 + c * 512);

    // QK(t+1): results consumed NEXT iteration -> no dependent wait here
#pragma unroll
    for (int mf = 0; mf < 2; ++mf)
#pragma unroll
        for (int i = 0; i < 16; ++i) stn[mf][i] = 0.f;
    __builtin_amdgcn_s_setprio(1);
#pragma unroll
    for (int c = 0; c < 4; ++c)
#pragma unroll
        for (int mf = 0; mf < 2; ++mf)
            stn[mf] = MFMA32(Kn[mf * 4 + c], qf[c], stn[mf]);
    __builtin_amdgcn_s_setprio(0);

    // softmax + PV of tile t (stc's MFMAs retired an iteration ago)
    attn_softpv(stc, vf, oacc, ls, h);
}

__global__ __launch_bounds__(256, 2) void attn_kernel(
    const bf16* __restrict__ q, const bf16* __restrict__ k,
    const bf16* __restrict__ vt, bf16* __restrict__ o0) {
    __shared__ bf16 lds[4 * 2112];  // epilogue transpose only (wave-private)

    const int t = threadIdx.x;
    const int w = t >> 6, lane = t & 63;
    const int q32 = lane & 31, h = lane >> 5;
    const int bh = blockIdx.x & 31;   // same-bh blocks share an XCD
    const int qb = blockIdx.x >> 5;   // 0..15 (128-row q tiles)
    const int qr0 = qb * 128 + w * 32;

    bf16x8 qf[4];
#pragma unroll
    for (int c = 0; c < 4; ++c)
        qf[c] = *(const bf16x8*)(q + (size_t)(bh * SS + qr0 + q32) * DD + c * 16 + h * 8);

    const bf16* kbase = k + (size_t)bh * 131072 + lane * 8;
    const bf16* vbase = vt + (size_t)bh * 131072 + lane * 8;

    f32x16 oacc[2];
#pragma unroll
    for (int mf = 0; mf < 2; ++mf)
#pragma unroll
        for (int i = 0; i < 16; ++i) oacc[mf][i] = 0.f;
    float ls[4] = {0.f, 0.f, 0.f, 0.f};

    // prologue: K(0)->Ka, K(1)->Kb, QK(0)->stA
    bf16x8 Ka[8], Kb[8];
#pragma unroll
    for (int mf = 0; mf < 2; ++mf)
#pragma unroll
        for (int c = 0; c < 4; ++c)
            Ka[mf * 4 + c] = *(const bf16x8*)(kbase + mf * 2048 + c * 512);
#pragma unroll
    for (int mf = 0; mf < 2; ++mf)
#pragma unroll
        for (int c = 0; c < 4; ++c)
            Kb[mf * 4 + c] = *(const bf16x8*)(kbase + 4096 + mf * 2048 + c * 512);

    f32x16 stA[2], stB[2];
#pragma unroll
    for (int mf = 0; mf < 2; ++mf)
#pragma unroll
        for (int i = 0; i < 16; ++i) stA[mf][i] = 0.f;
    __builtin_amdgcn_s_setprio(1);
#pragma unroll
    for (int c = 0; c < 4; ++c)
#pragma unroll
        for (int mf = 0; mf < 2; ++mf)
            stA[mf] = MFMA32(Ka[mf * 4 + c], qf[c], stA[mf]);
    __builtin_amdgcn_s_setprio(0);

    // pipeline: even t -> (stA,stB,Kb,Ka); odd t -> (stB,stA,Ka,Kb)
    for (int p = 0; p < NT / 2 - 1; ++p) {
        attn_pipe(2 * p,     kbase, vbase, qf, stA, stB, Kb, Ka, oacc, ls, h);
        attn_pipe(2 * p + 1, kbase, vbase, qf, stB, stA, Ka, Kb, oacc, ls, h);
    }
    attn_pipe(NT - 2, kbase, vbase, qf, stA, stB, Kb, Ka, oacc, ls, h);

    // drain: tile NT-1 (scores in stB)
    {
        bf16x8 vf[8];
#pragma unroll
        for (int mf = 0; mf < 2; ++mf)
#pragma unroll
            for (int c = 0; c < 4; ++c)
                vf[mf * 4 + c] =
                    *(const bf16x8*)(vbase + (NT - 1) * 4096 + mf * 2048 + c * 512);
        attn_softpv(stB, vf, oacc, ls, h);
    }

    float lsum = (ls[0] + ls[1]) + (ls[2] + ls[3]);
    lsum += __shfl_xor(lsum, 32);
    const float inv = 1.f / lsum;

    bf16* ob = lds + w * 2112;  // 32 rows x stride 66, wave-private
#pragma unroll
    for (int mf = 0; mf < 2; ++mf)
#pragma unroll
        for (int rp = 0; rp < 8; ++rp) {
            const int d = 32 * mf + 2 * (rp & 1) + 8 * (rp >> 1) + 4 * h;
            *(u32*)(ob + q32 * 66 + d) =
                pkbf(oacc[mf][2 * rp] * inv, oacc[mf][2 * rp + 1] * inv);
        }
    __syncthreads();

    const int b = bh >> 4, head = bh & 15;
    const int half = lane & 1;
    const int r = lane >> 1;
#pragma unroll
    for (int i = 0; i < 4; ++i) {
        bf16x8 val = *(const bf16x8*)(ob + r * 66 + half * 32 + i * 8);
        *(bf16x8*)(o0 + (size_t)(b * SS + qr0 + r) * EE + head * DD +
                   half * 32 + i * 8) = val;
    }
}

// ---------------------------------------------------------------------------
// Single scratch layout, everything in d_ws (40 MiB).  d_out written exactly
// once, by gemm_o.
// ---------------------------------------------------------------------------
extern "C" void kernel_launch(void* const* d_in, const int* in_sizes, int n_in,
                              void* d_out, int out_size, void* d_ws, size_t ws_size,
                              hipStream_t stream) {
    const float* query = (const float*)d_in[0];
    const float* xi    = (const float*)d_in[1];
    const float* Wq = (const float*)d_in[2];  const float* bq = (const float*)d_in[3];
    const float* Wk = (const float*)d_in[4];  const float* bk = (const float*)d_in[5];
    const float* Wv = (const float*)d_in[6];  const float* bv = (const float*)d_in[7];
    const float* Wo = (const float*)d_in[8];  const float* bo = (const float*)d_in[9];
    const float* ew1 = (const float*)d_in[10]; const float* eb1 = (const float*)d_in[11];
    const float* lng = (const float*)d_in[12]; const float* lnb = (const float*)d_in[13];
    const float* ew2 = (const float*)d_in[14]; const float* eb2 = (const float*)d_in[15];
    const float* gate = (const float*)d_in[16];
    float* out = (float*)d_out;

    char* ws = (char*)d_ws;
    const size_t SZ = (size_t)MM * EE * sizeof(bf16);   // 8 MB
    const size_t WSZ = (size_t)EE * EE * sizeof(bf16);  // 2 MB per transposed weight

    bf16* queryc = (bf16*)(ws);            // dead after gemm_qkv
    bf16* p0     = (bf16*)(ws);            // attn output overlays queryc
    bf16* qws    = (bf16*)(ws + SZ);
    bf16* kws    = (bf16*)(ws + 2 * SZ);
    bf16* vtws   = (bf16*)(ws + 3 * SZ);
    bf16* wqT    = (bf16*)(ws + 4 * SZ);
    bf16* wkT    = (bf16*)(ws + 4 * SZ + WSZ);
    bf16* wvT    = (bf16*)(ws + 4 * SZ + 2 * WSZ);
    bf16* woT    = (bf16*)(ws + 4 * SZ + 3 * WSZ);
    float* adaptws = (float*)(ws + 4 * SZ + 4 * WSZ);

    prep_kernel<<<3074, 256, 0, stream>>>(query, queryc, Wq, Wk, Wv, Wo,
                                          wqT, wkT, wvT, woT,
                                          xi, ew1, eb1, lng, lnb, ew2, eb2, gate,
                                          adaptws);

    // combined QK (512) + V^T (256) = 768 blocks = 3/CU
    gemm_qkv<<<768, 256, 0, stream>>>(queryc, wqT, wvT, bq, bk, bv, adaptws,
                                      qws, vtws);

    // 32 bh x 16 q-tiles = 512 blocks of 256 threads (full K-range per block)
    attn_kernel<<<512, 256, 0, stream>>>(qws, kws, vtws, p0);

    gemm_o<<<dim3(MM / 128, EE / 64), 256, 0, stream>>>(p0, woT, bo, out);
}

// Round 7
// 212.599 us; speedup vs baseline: 1.1787x; 1.1787x over previous
//
#include <hip/hip_runtime.h>

typedef __bf16 bf16;
typedef __attribute__((ext_vector_type(8))) __bf16 bf16x8;
typedef __attribute__((ext_vector_type(4))) float f32x4;
typedef __attribute__((ext_vector_type(16))) float f32x16;
typedef unsigned int u32;

#define MFMA16(a, b, c) __builtin_amdgcn_mfma_f32_16x16x32_bf16((a), (b), (c), 0, 0, 0)
#define MFMA32(a, b, c) __builtin_amdgcn_mfma_f32_32x32x16_bf16((a), (b), (c), 0, 0, 0)

// Problem constants
#define BB 2
#define SS 2048
#define EE 1024
#define HH 16
#define DD 64
#define MM (BB * SS)  // 4096
#define NT (SS / 64)  // 32 K-tiles

__device__ inline f32x4 zero4() {
    f32x4 z; z.x = 0.f; z.y = 0.f; z.z = 0.f; z.w = 0.f; return z;
}

// async global->LDS DMA, 16B per lane.  LDS dest = wave-uniform base + lane*16.
__device__ __forceinline__ void gload16(const bf16* g, bf16* l) {
    __builtin_amdgcn_global_load_lds(
        (const __attribute__((address_space(1))) u32*)(const void*)g,
        (__attribute__((address_space(3))) u32*)(void*)l,
        16, 0, 0);
}

__device__ __forceinline__ u32 pkbf(float a, float b) {
    union { __bf16 h; unsigned short s; } ua, ub;
    ua.h = (__bf16)a; ub.h = (__bf16)b;
    return (u32)ua.s | ((u32)ub.s << 16);
}

// ---------------------------------------------------------------------------
// Kernel 1: fused prep.
// ---------------------------------------------------------------------------
__global__ __launch_bounds__(256) void prep_kernel(
    const float* __restrict__ query, bf16* __restrict__ qc,
    const float* __restrict__ s0, const float* __restrict__ s1,
    const float* __restrict__ s2, const float* __restrict__ s3,
    bf16* __restrict__ d0, bf16* __restrict__ d1,
    bf16* __restrict__ d2, bf16* __restrict__ d3,
    const float* __restrict__ xi, const float* __restrict__ w1,
    const float* __restrict__ b1, const float* __restrict__ lng,
    const float* __restrict__ lnb, const float* __restrict__ w2,
    const float* __restrict__ b2, const float* __restrict__ gate,
    float* __restrict__ adapt) {
    __shared__ bf16 tile[64 * 72];
    const int bid = blockIdx.x;
    const int t = threadIdx.x;

    if (bid < 2048) {
        const int i = (bid * 256 + t) * 8;
        float4 a = *(const float4*)(query + i);
        float4 b = *(const float4*)(query + i + 4);
        bf16 tmp[8];
        tmp[0] = (bf16)a.x; tmp[1] = (bf16)a.y; tmp[2] = (bf16)a.z; tmp[3] = (bf16)a.w;
        tmp[4] = (bf16)b.x; tmp[5] = (bf16)b.y; tmp[6] = (bf16)b.z; tmp[7] = (bf16)b.w;
        *(uint4*)(qc + i) = *(uint4*)tmp;
    } else if (bid < 3072) {
        const int m = (bid - 2048) >> 8;
        const int idx0 = (bid - 2048) & 255;
        const float* W = (m == 0) ? s0 : (m == 1) ? s1 : (m == 2) ? s2 : s3;
        bf16* Wt = (m == 0) ? d0 : (m == 1) ? d1 : (m == 2) ? d2 : d3;
        const int k0 = (idx0 >> 4) * 64, n0 = (idx0 & 15) * 64;
#pragma unroll
        for (int i = 0; i < 2; ++i) {
            int idx = i * 256 + t;
            int r = idx >> 3, c = (idx & 7) * 8;
            float4 a = *(const float4*)(W + (k0 + r) * EE + n0 + c);
            float4 b = *(const float4*)(W + (k0 + r) * EE + n0 + c + 4);
            bf16 tmp[8];
            tmp[0] = (bf16)a.x; tmp[1] = (bf16)a.y; tmp[2] = (bf16)a.z; tmp[3] = (bf16)a.w;
            tmp[4] = (bf16)b.x; tmp[5] = (bf16)b.y; tmp[6] = (bf16)b.z; tmp[7] = (bf16)b.w;
            *(uint4*)(tile + r * 72 + c) = *(uint4*)tmp;
        }
        __syncthreads();
#pragma unroll
        for (int i = 0; i < 2; ++i) {
            int idx = i * 256 + t;
            int n = idx >> 3, kc = (idx & 7) * 8;
            bf16 tmp[8];
#pragma unroll
            for (int j = 0; j < 8; ++j) tmp[j] = tile[(kc + j) * 72 + n];
            *(uint4*)(Wt + (n0 + n) * EE + k0 + kc) = *(uint4*)tmp;
        }
    } else {
        const int b = bid - 3072;
        float* xs = (float*)tile;
        if (t < 64) {
            const float xiv = xi[b];
            float xv = 0.f;
            if (t < 32) xv = xiv * w1[t] + b1[t];
            float sm = xv;
            for (int off = 1; off < 32; off <<= 1) sm += __shfl_xor(sm, off);
            const float mu = sm * (1.f / 32.f);
            float dv = (t < 32) ? (xv - mu) : 0.f;
            float s2 = dv * dv;
            for (int off = 1; off < 32; off <<= 1) s2 += __shfl_xor(s2, off);
            const float var = s2 * (1.f / 32.f);
            if (t < 32) {
                float xn = (xv - mu) * rsqrtf(var + 1e-5f) * lng[t] + lnb[t];
                float ge = 0.5f * xn * (1.f + erff(xn * 0.70710678118654752f));
                xs[t] = ge;
            }
        }
        __syncthreads();
        if (t < 64) {
            float acc = b2[t];
            for (int j = 0; j < 32; ++j) acc += xs[j] * w2[j * DD + t];
            for (int h = 0; h < HH; ++h) {
                float sg = 1.f / (1.f + __expf(-gate[h]));
                adapt[(b * HH + h) * DD + t] = 1.f + sg * acc;
            }
        }
    }
}

// ---------------------------------------------------------------------------
// Kernel 2: QKV GEMM — 128x128 tile, BK=32, dbuf DMA, one barrier/iter.
// q-scale folds 0.125*log2(e) so attention uses bare v_exp_f32 (exp2).
// K and V^T outputs in PERMUTED TILE LAYOUT (R4):
//   idx = bh*131072 + kt*4096 + mf*2048 + c*512 + lane*8 + j
// Epilogue v2 (R5, verified): scaled results -> XOR-swizzled LDS tile ->
// 8 x dwordx4 stores/thread (was 64 scalar scattered stores; VMEM-issue
// bound).  bias/adapt hoisted to per-column FMA factors.
// ---------------------------------------------------------------------------
__global__ __launch_bounds__(256, 3) void gemm_qkv(
    const bf16* __restrict__ Aq, const bf16* __restrict__ Bqk,
    const bf16* __restrict__ Av,
    const float* __restrict__ bias, const float* __restrict__ bias2,
    const float* __restrict__ bias3, const float* __restrict__ adapt,
    bf16* __restrict__ outqk, bf16* __restrict__ outvt) {
    __shared__ bf16 sh[16384];  // main loop: As/Bs; epilogue: 128x128 tile
    bf16* As = sh;
    bf16* Bs = sh + 8192;

    const int t = threadIdx.x;
    const int w = t >> 6, lane = t & 63;
    const int mrow = lane & 15, quad = lane >> 4;
    const int wm = (w & 1) * 64, wn = (w >> 1) * 64;

    int md, bx, by;
    const bf16 *Ap, *Bp;
    int bid = blockIdx.x;
    if (bid < 512) { md = 5; bx = bid & 31; by = bid >> 5; Ap = Aq; Bp = Bqk; }
    else { md = 4; bid -= 512; bx = bid & 7; by = bid >> 3; Ap = Av; Bp = Aq; }
    const int m0 = bx * 128, n0 = by * 128;
    const int m2 = (md == 5) ? (by >> 3) : 0;  // 0=Q, 1=K (block-uniform)

    f32x4 acc[4][4];
#pragma unroll
    for (int i = 0; i < 4; ++i)
#pragma unroll
        for (int j = 0; j < 4; ++j) acc[i][j] = zero4();

    const int dr = lane >> 2;
    const int dcg = ((lane & 3) ^ (dr & 3)) * 8;
    const bf16* Ag = Ap + (size_t)(m0 + w * 16 + dr) * EE + dcg;
    const bf16* Bg = Bp + (size_t)(n0 + w * 16 + dr) * EE + dcg;
    bf16* Al = As + (w * 16) * 32;
    bf16* Bl = Bs + (w * 16) * 32;

    gload16(Ag, Al);
    gload16(Ag + 64 * EE, Al + 64 * 32);
    gload16(Bg, Bl);
    gload16(Bg + 64 * EE, Bl + 64 * 32);

    for (int kt = 0; kt < 32; ++kt) {
        __syncthreads();
        if (kt < 31) {
            const int kn = (kt + 1) * 32;
            const int nb = (kt + 1) & 1;
            gload16(Ag + kn, Al + nb * 4096);
            gload16(Ag + 64 * EE + kn, Al + nb * 4096 + 64 * 32);
            gload16(Bg + kn, Bl + nb * 4096);
            gload16(Bg + 64 * EE + kn, Bl + nb * 4096 + 64 * 32);
        }
        const bf16* Ab = As + (kt & 1) * 4096;
        const bf16* Bb = Bs + (kt & 1) * 4096;
        const int sw = (quad ^ (mrow & 3)) * 8;
        bf16x8 af[4], bfr[4];
#pragma unroll
        for (int i = 0; i < 4; ++i)
            af[i] = *(const bf16x8*)(Ab + (wm + i * 16 + mrow) * 32 + sw);
#pragma unroll
        for (int j = 0; j < 4; ++j)
            bfr[j] = *(const bf16x8*)(Bb + (wn + j * 16 + mrow) * 32 + sw);
#pragma unroll
        for (int i = 0; i < 4; ++i)
#pragma unroll
            for (int j = 0; j < 4; ++j)
                acc[i][j] = MFMA16(af[i], bfr[j], acc[i][j]);
    }

    // ---- epilogue v2: scale -> swizzled LDS -> vectorized stores ----
    __syncthreads();  // staging LDS now dead; safe to overwrite

    if (md == 5) {
        const int bq_ = m0 >> 11;
        float cmul[4], cadd[4];
#pragma unroll
        for (int j = 0; j < 4; ++j) {
            const int cl = (n0 & 1023) + wn + j * 16 + mrow;
            const int hh = cl >> 6, dd2 = cl & 63;
            const float ad = adapt[(bq_ * HH + hh) * DD + dd2];
            const float sc = m2 ? 1.f : 0.18033688011113811f;
            cmul[j] = ad * sc;
            cadd[j] = (m2 ? bias2[cl] : bias[cl]) * ad * sc;
        }
#pragma unroll
        for (int i = 0; i < 4; ++i)
#pragma unroll
            for (int j = 0; j < 4; ++j) {
                const int lcol = wn + j * 16 + mrow;
#pragma unroll
                for (int r = 0; r < 4; ++r) {
                    const int lrow = wm + i * 16 + quad * 4 + r;
                    const float v = acc[i][j][r] * cmul[j] + cadd[j];
                    *(bf16*)((char*)sh + lrow * 256 +
                             ((lcol * 2) ^ ((lrow & 15) << 4))) = (bf16)v;
                }
            }
    } else {
        float radd[16];
#pragma unroll
        for (int i = 0; i < 4; ++i)
#pragma unroll
            for (int r = 0; r < 4; ++r)
                radd[i * 4 + r] = bias3[m0 + wm + i * 16 + quad * 4 + r];
#pragma unroll
        for (int i = 0; i < 4; ++i)
#pragma unroll
            for (int j = 0; j < 4; ++j) {
                const int lcol = wn + j * 16 + mrow;
#pragma unroll
                for (int r = 0; r < 4; ++r) {
                    const int lrow = wm + i * 16 + quad * 4 + r;
                    const float v = acc[i][j][r] + radd[i * 4 + r];
                    *(bf16*)((char*)sh + lrow * 256 +
                             ((lcol * 2) ^ ((lrow & 15) << 4))) = (bf16)v;
                }
            }
    }
    __syncthreads();

#pragma unroll
    for (int p = 0; p < 8; ++p) {
        const int lrow = p * 16 + (t >> 4);
        const int lcol0 = (t & 15) * 8;
        bf16x8 val = *(const bf16x8*)((const char*)sh + lrow * 256 +
                                      ((lcol0 * 2) ^ ((lrow & 15) << 4)));
        if (md == 5) {
            const int bq_ = m0 >> 11;
            const int s_ = (m0 + lrow) & (SS - 1);
            const int cl = (n0 & 1023) + lcol0;
            const int hh = cl >> 6, d0 = cl & 63;
            if (!m2) {
                *(bf16x8*)(outqk + ((size_t)(bq_ * HH + hh) * SS + s_) * DD + d0) = val;
            } else {
                const size_t base = (size_t)MM * EE + (size_t)(bq_ * HH + hh) * 131072;
                const int a2 = (s_ >> 6) * 4096 + ((s_ >> 5) & 1) * 2048 +
                               (d0 >> 4) * 512 +
                               ((s_ & 31) + ((d0 >> 3) & 1) * 32) * 8;
                *(bf16x8*)(outqk + base + a2) = val;
            }
        } else {
            const int rowv = m0 + lrow;
            const int hv = rowv >> 6, dv = rowv & 63;
            const int colv = n0 + lcol0;
            const int bv_ = colv >> 11, sv = colv & (SS - 1);
            const size_t base = (size_t)(bv_ * HH + hv) * 131072;
            const int a2 = (sv >> 6) * 4096 + (dv >> 5) * 2048 +
                           ((sv >> 4) & 3) * 512 +
                           ((dv & 31) + ((sv >> 3) & 1) * 32) * 8;
            *(bf16x8*)(outvt + base + a2) = val;
        }
    }
}

// ---------------------------------------------------------------------------
// Kernel 3: final GEMM (R5 epilogue v2, verified).
// ---------------------------------------------------------------------------
__global__ __launch_bounds__(256, 3) void gemm_o(
    const bf16* __restrict__ A, const bf16* __restrict__ Bt,
    const float* __restrict__ bias, float* __restrict__ outf) {
    __shared__ bf16 As[2 * 128 * 64];  // 32KB; epilogue reuses as 128x64 f32
    __shared__ bf16 Bs[2 * 64 * 64];

    const int t = threadIdx.x;
    const int w = t >> 6, lane = t & 63;
    const int mrow = lane & 15, quad = lane >> 4;
    const int m0 = blockIdx.x * 128, n0 = blockIdx.y * 64;

    f32x4 acc[2][4];
#pragma unroll
    for (int i = 0; i < 2; ++i)
#pragma unroll
        for (int j = 0; j < 4; ++j) acc[i][j] = zero4();

    const int grow = lane >> 3;
    const int gsw = ((lane & 7) ^ grow) * 8;
    const bf16* Ag = A + (size_t)(m0 + w * 32 + grow) * EE + gsw;
    const bf16* Bg = Bt + (size_t)(n0 + w * 16 + grow) * EE + gsw;
    bf16* Al = As + (w * 32) * 64;
    bf16* Bl = Bs + (w * 16) * 64;

#pragma unroll
    for (int i = 0; i < 4; ++i) gload16(Ag + i * 8 * EE, Al + i * 8 * 64);
#pragma unroll
    for (int i = 0; i < 2; ++i) gload16(Bg + i * 8 * EE, Bl + i * 8 * 64);

    for (int kt = 0; kt < 16; ++kt) {
        __syncthreads();
        if (kt < 15) {
            const int kn = (kt + 1) * 64;
            const int nb = (kt + 1) & 1;
#pragma unroll
            for (int i = 0; i < 4; ++i)
                gload16(Ag + i * 8 * EE + kn, Al + nb * 8192 + i * 8 * 64);
#pragma unroll
            for (int i = 0; i < 2; ++i)
                gload16(Bg + i * 8 * EE + kn, Bl + nb * 4096 + i * 8 * 64);
        }
        const bf16* Ab = As + (kt & 1) * 8192;
        const bf16* Bb = Bs + (kt & 1) * 4096;
#pragma unroll
        for (int ks = 0; ks < 2; ++ks) {
            const int cg = ks * 4 + quad;
            const int sw = (cg ^ (mrow & 7)) * 8;
            bf16x8 af[2], bfr[4];
#pragma unroll
            for (int mi = 0; mi < 2; ++mi)
                af[mi] = *(const bf16x8*)(Ab + (w * 32 + mi * 16 + mrow) * 64 + sw);
#pragma unroll
            for (int nj = 0; nj < 4; ++nj)
                bfr[nj] = *(const bf16x8*)(Bb + (nj * 16 + mrow) * 64 + sw);
#pragma unroll
            for (int mi = 0; mi < 2; ++mi)
#pragma unroll
                for (int nj = 0; nj < 4; ++nj)
                    acc[mi][nj] = MFMA16(af[mi], bfr[nj], acc[mi][nj]);
        }
    }

    // ---- epilogue v2 ----
    __syncthreads();  // staging LDS dead
    char* fs = (char*)As;  // 128 rows x 256B (64 f32), swizzled
    float cadd[4];
#pragma unroll
    for (int nj = 0; nj < 4; ++nj) cadd[nj] = bias[n0 + nj * 16 + mrow];
#pragma unroll
    for (int mi = 0; mi < 2; ++mi)
#pragma unroll
        for (int nj = 0; nj < 4; ++nj) {
            const int lcol = nj * 16 + mrow;
#pragma unroll
            for (int r = 0; r < 4; ++r) {
                const int lrow = w * 32 + mi * 16 + quad * 4 + r;
                *(float*)(fs + lrow * 256 + ((lcol * 4) ^ ((lrow & 15) << 4))) =
                    acc[mi][nj][r] + cadd[nj];
            }
        }
    __syncthreads();

#pragma unroll
    for (int p = 0; p < 8; ++p) {
        const int lrow = p * 16 + (t >> 4);
        const int lcol0 = (t & 15) * 4;
        float4 val = *(const float4*)(fs + lrow * 256 +
                                      ((lcol0 * 4) ^ ((lrow & 15) << 4)));
        *(float4*)(outf + (size_t)(m0 + lrow) * EE + n0 + lcol0) = val;
    }
}

// ---------------------------------------------------------------------------
// Kernel 4: flash attention — R7: R5 structure (verified 54us) + raw
// s_barrier wave-clustering.
// R6 post-mortem: reg-pipelined 2nd st spilled (WRITE_SIZE 8->79MB scratch,
// 2x regression) — DEAD END.
// R7 theory: all 4 waves/block read IDENTICAL K/V addresses -> 1GB L2 reads
// for 256MB unique (4x dedup loss); 1GB/34.5TB/s ~= 30us floor ~ R5's 54us
// => L2-BW-bound.  A raw s_barrier (__builtin_amdgcn_s_barrier: NO waitcnt
// drain, unlike __syncthreads) per K-tile keeps the 4 waves on the same
// 16KB tile working set so the CU's 32KB L1 serves 3 of 4 reads.
// Dead ends: split-K (nondet), K-tile 32/128, gload_lds staging (drain-
// coupled barriers, R1-R3 61us invariant), reg-pipeline (R6 spill),
// grid reshaping (R2/R3 invariant).
// ---------------------------------------------------------------------------
__device__ __forceinline__ void attn_step(
    int kt, const bf16* kbase, const bf16* vbase,
    const bf16x8 (&qf)[4], bf16x8 (&KU)[8], bf16x8 (&KP)[8],
    f32x16 (&oacc)[2], float (&ls)[4], int h) {
    // raw wave-sync: cluster the 4 waves on this tile for L1 reuse
    __builtin_amdgcn_s_barrier();

    bf16x8 vf[8];
#pragma unroll
    for (int mf = 0; mf < 2; ++mf)
#pragma unroll
        for (int c = 0; c < 4; ++c)
            vf[mf * 4 + c] = *(const bf16x8*)(vbase + kt * 4096 + mf * 2048 + c * 512);

    f32x16 st[2];
#pragma unroll
    for (int mf = 0; mf < 2; ++mf)
#pragma unroll
        for (int i = 0; i < 16; ++i) st[mf][i] = 0.f;
    __builtin_amdgcn_s_setprio(1);
#pragma unroll
    for (int c = 0; c < 4; ++c)
#pragma unroll
        for (int mf = 0; mf < 2; ++mf)
            st[mf] = MFMA32(KU[mf * 4 + c], qf[c], st[mf]);
    __builtin_amdgcn_s_setprio(0);

    const int ktp = kt + (kt < NT - 1 ? 1 : 0);
#pragma unroll
    for (int mf = 0; mf < 2; ++mf)
#pragma unroll
        for (int c = 0; c < 4; ++c)
            KP[mf * 4 + c] = *(const bf16x8*)(kbase + ktp * 4096 + mf * 2048 + c * 512);

    u32 P32[2][8];
#pragma unroll
    for (int mf = 0; mf < 2; ++mf)
#pragma unroll
        for (int rp = 0; rp < 8; ++rp) {
            float pa = __builtin_amdgcn_exp2f(st[mf][2 * rp]);
            float pb = __builtin_amdgcn_exp2f(st[mf][2 * rp + 1]);
            ls[rp & 3] += pa + pb;
            P32[mf][rp] = pkbf(pa, pb);
        }

#pragma unroll
    for (int c = 0; c < 4; ++c) {
        const int mfs = c >> 1;
        const int ro = (c & 1) * 4;
        union { u32 u[4]; bf16x8 v; } pb;
        {
            u32 vA0 = P32[mfs][ro + 0], vA1 = P32[mfs][ro + 1];
            u32 vB0 = P32[mfs][ro + 2], vB1 = P32[mfs][ro + 3];
            u32 prep0 = h ? vA0 : vB0;
            u32 prep1 = h ? vA1 : vB1;
            u32 sh0 = __shfl_xor(prep0, 32);
            u32 sh1 = __shfl_xor(prep1, 32);
            pb.u[0] = h ? sh0 : vA0;
            pb.u[1] = h ? sh1 : vA1;
            pb.u[2] = h ? vB0 : sh0;
            pb.u[3] = h ? vB1 : sh1;
        }
        __builtin_amdgcn_s_setprio(1);
#pragma unroll
        for (int mf = 0; mf < 2; ++mf)
            oacc[mf] = MFMA32(vf[mf * 4 + c], pb.v, oacc[mf]);
        __builtin_amdgcn_s_setprio(0);
    }
}

__global__ __launch_bounds__(256, 2) void attn_kernel(
    const bf16* __restrict__ q, const bf16* __restrict__ k,
    const bf16* __restrict__ vt, bf16* __restrict__ o0) {
    __shared__ bf16 lds[4 * 2112];  // epilogue transpose only (wave-private)

    const int t = threadIdx.x;
    const int w = t >> 6, lane = t & 63;
    const int q32 = lane & 31, h = lane >> 5;
    const int bh = blockIdx.x & 31;   // same-bh blocks share an XCD
    const int qb = blockIdx.x >> 5;   // 0..15 (128-row q tiles)
    const int qr0 = qb * 128 + w * 32;

    bf16x8 qf[4];
#pragma unroll
    for (int c = 0; c < 4; ++c)
        qf[c] = *(const bf16x8*)(q + (size_t)(bh * SS + qr0 + q32) * DD + c * 16 + h * 8);

    const bf16* kbase = k + (size_t)bh * 131072 + lane * 8;
    const bf16* vbase = vt + (size_t)bh * 131072 + lane * 8;

    f32x16 oacc[2];
#pragma unroll
    for (int mf = 0; mf < 2; ++mf)
#pragma unroll
        for (int i = 0; i < 16; ++i) oacc[mf][i] = 0.f;
    float ls[4] = {0.f, 0.f, 0.f, 0.f};

    bf16x8 Ka[8], Kb[8];
#pragma unroll
    for (int mf = 0; mf < 2; ++mf)
#pragma unroll
        for (int c = 0; c < 4; ++c)
            Ka[mf * 4 + c] = *(const bf16x8*)(kbase + mf * 2048 + c * 512);

    for (int kt2 = 0; kt2 < NT / 2; ++kt2) {
        attn_step(2 * kt2,     kbase, vbase, qf, Ka, Kb, oacc, ls, h);
        attn_step(2 * kt2 + 1, kbase, vbase, qf, Kb, Ka, oacc, ls, h);
    }

    float lsum = (ls[0] + ls[1]) + (ls[2] + ls[3]);
    lsum += __shfl_xor(lsum, 32);
    const float inv = 1.f / lsum;

    bf16* ob = lds + w * 2112;  // 32 rows x stride 66, wave-private
#pragma unroll
    for (int mf = 0; mf < 2; ++mf)
#pragma unroll
        for (int rp = 0; rp < 8; ++rp) {
            const int d = 32 * mf + 2 * (rp & 1) + 8 * (rp >> 1) + 4 * h;
            *(u32*)(ob + q32 * 66 + d) =
                pkbf(oacc[mf][2 * rp] * inv, oacc[mf][2 * rp + 1] * inv);
        }
    __syncthreads();

    const int b = bh >> 4, head = bh & 15;
    const int half = lane & 1;
    const int r = lane >> 1;
#pragma unroll
    for (int i = 0; i < 4; ++i) {
        bf16x8 val = *(const bf16x8*)(ob + r * 66 + half * 32 + i * 8);
        *(bf16x8*)(o0 + (size_t)(b * SS + qr0 + r) * EE + head * DD +
                   half * 32 + i * 8) = val;
    }
}

// ---------------------------------------------------------------------------
// Single scratch layout, everything in d_ws (40 MiB).  d_out written exactly
// once, by gemm_o.
// ---------------------------------------------------------------------------
extern "C" void kernel_launch(void* const* d_in, const int* in_sizes, int n_in,
                              void* d_out, int out_size, void* d_ws, size_t ws_size,
                              hipStream_t stream) {
    const float* query = (const float*)d_in[0];
    const float* xi    = (const float*)d_in[1];
    const float* Wq = (const float*)d_in[2];  const float* bq = (const float*)d_in[3];
    const float* Wk = (const float*)d_in[4];  const float* bk = (const float*)d_in[5];
    const float* Wv = (const float*)d_in[6];  const float* bv = (const float*)d_in[7];
    const float* Wo = (const float*)d_in[8];  const float* bo = (const float*)d_in[9];
    const float* ew1 = (const float*)d_in[10]; const float* eb1 = (const float*)d_in[11];
    const float* lng = (const float*)d_in[12]; const float* lnb = (const float*)d_in[13];
    const float* ew2 = (const float*)d_in[14]; const float* eb2 = (const float*)d_in[15];
    const float* gate = (const float*)d_in[16];
    float* out = (float*)d_out;

    char* ws = (char*)d_ws;
    const size_t SZ = (size_t)MM * EE * sizeof(bf16);   // 8 MB
    const size_t WSZ = (size_t)EE * EE * sizeof(bf16);  // 2 MB per transposed weight

    bf16* queryc = (bf16*)(ws);            // dead after gemm_qkv
    bf16* p0     = (bf16*)(ws);            // attn output overlays queryc
    bf16* qws    = (bf16*)(ws + SZ);
    bf16* kws    = (bf16*)(ws + 2 * SZ);
    bf16* vtws   = (bf16*)(ws + 3 * SZ);
    bf16* wqT    = (bf16*)(ws + 4 * SZ);
    bf16* wkT    = (bf16*)(ws + 4 * SZ + WSZ);
    bf16* wvT    = (bf16*)(ws + 4 * SZ + 2 * WSZ);
    bf16* woT    = (bf16*)(ws + 4 * SZ + 3 * WSZ);
    float* adaptws = (float*)(ws + 4 * SZ + 4 * WSZ);

    prep_kernel<<<3074, 256, 0, stream>>>(query, queryc, Wq, Wk, Wv, Wo,
                                          wqT, wkT, wvT, woT,
                                          xi, ew1, eb1, lng, lnb, ew2, eb2, gate,
                                          adaptws);

    // combined QK (512) + V^T (256) = 768 blocks = 3/CU
    gemm_qkv<<<768, 256, 0, stream>>>(queryc, wqT, wvT, bq, bk, bv, adaptws,
                                      qws, vtws);

    // 32 bh x 16 q-tiles = 512 blocks of 256 threads (full K-range per block)
    attn_kernel<<<512, 256, 0, stream>>>(qws, kws, vtws, p0);

    gemm_o<<<dim3(MM / 128, EE / 64), 256, 0, stream>>>(p0, woT, bo, out);
}

// Round 8
// 206.675 us; speedup vs baseline: 1.2125x; 1.0287x over previous
//
#include <hip/hip_runtime.h>

typedef __bf16 bf16;
typedef __attribute__((ext_vector_type(8))) __bf16 bf16x8;
typedef __attribute__((ext_vector_type(4))) float f32x4;
typedef __attribute__((ext_vector_type(16))) float f32x16;
typedef unsigned int u32;

#define MFMA16(a, b, c) __builtin_amdgcn_mfma_f32_16x16x32_bf16((a), (b), (c), 0, 0, 0)
#define MFMA32(a, b, c) __builtin_amdgcn_mfma_f32_32x32x16_bf16((a), (b), (c), 0, 0, 0)

// Problem constants
#define BB 2
#define SS 2048
#define EE 1024
#define HH 16
#define DD 64
#define MM (BB * SS)  // 4096
#define NT (SS / 64)  // 32 K-tiles

__device__ inline f32x4 zero4() {
    f32x4 z; z.x = 0.f; z.y = 0.f; z.z = 0.f; z.w = 0.f; return z;
}

// async global->LDS DMA, 16B per lane.  LDS dest = wave-uniform base + lane*16.
__device__ __forceinline__ void gload16(const bf16* g, bf16* l) {
    __builtin_amdgcn_global_load_lds(
        (const __attribute__((address_space(1))) u32*)(const void*)g,
        (__attribute__((address_space(3))) u32*)(void*)l,
        16, 0, 0);
}

__device__ __forceinline__ u32 pkbf(float a, float b) {
    union { __bf16 h; unsigned short s; } ua, ub;
    ua.h = (__bf16)a; ub.h = (__bf16)b;
    return (u32)ua.s | ((u32)ub.s << 16);
}

// lane[i] (i<32) keeps lo, receives src.lo into hi... precisely:
// a' = {a.lo, b.lo}, b' = {a.hi, b.hi} — the exact redistribution softmax->PV
// needs (replaces 2 shfl + 6 selects per pair).  gfx950 instruction.
#define PSWAP(a, b) asm("v_permlane32_swap_b32 %0, %1" : "+v"(a), "+v"(b))

// ---------------------------------------------------------------------------
// Kernel 1: fused prep.
// ---------------------------------------------------------------------------
__global__ __launch_bounds__(256) void prep_kernel(
    const float* __restrict__ query, bf16* __restrict__ qc,
    const float* __restrict__ s0, const float* __restrict__ s1,
    const float* __restrict__ s2, const float* __restrict__ s3,
    bf16* __restrict__ d0, bf16* __restrict__ d1,
    bf16* __restrict__ d2, bf16* __restrict__ d3,
    const float* __restrict__ xi, const float* __restrict__ w1,
    const float* __restrict__ b1, const float* __restrict__ lng,
    const float* __restrict__ lnb, const float* __restrict__ w2,
    const float* __restrict__ b2, const float* __restrict__ gate,
    float* __restrict__ adapt) {
    __shared__ bf16 tile[64 * 72];
    const int bid = blockIdx.x;
    const int t = threadIdx.x;

    if (bid < 2048) {
        const int i = (bid * 256 + t) * 8;
        float4 a = *(const float4*)(query + i);
        float4 b = *(const float4*)(query + i + 4);
        bf16 tmp[8];
        tmp[0] = (bf16)a.x; tmp[1] = (bf16)a.y; tmp[2] = (bf16)a.z; tmp[3] = (bf16)a.w;
        tmp[4] = (bf16)b.x; tmp[5] = (bf16)b.y; tmp[6] = (bf16)b.z; tmp[7] = (bf16)b.w;
        *(uint4*)(qc + i) = *(uint4*)tmp;
    } else if (bid < 3072) {
        const int m = (bid - 2048) >> 8;
        const int idx0 = (bid - 2048) & 255;
        const float* W = (m == 0) ? s0 : (m == 1) ? s1 : (m == 2) ? s2 : s3;
        bf16* Wt = (m == 0) ? d0 : (m == 1) ? d1 : (m == 2) ? d2 : d3;
        const int k0 = (idx0 >> 4) * 64, n0 = (idx0 & 15) * 64;
#pragma unroll
        for (int i = 0; i < 2; ++i) {
            int idx = i * 256 + t;
            int r = idx >> 3, c = (idx & 7) * 8;
            float4 a = *(const float4*)(W + (k0 + r) * EE + n0 + c);
            float4 b = *(const float4*)(W + (k0 + r) * EE + n0 + c + 4);
            bf16 tmp[8];
            tmp[0] = (bf16)a.x; tmp[1] = (bf16)a.y; tmp[2] = (bf16)a.z; tmp[3] = (bf16)a.w;
            tmp[4] = (bf16)b.x; tmp[5] = (bf16)b.y; tmp[6] = (bf16)b.z; tmp[7] = (bf16)b.w;
            *(uint4*)(tile + r * 72 + c) = *(uint4*)tmp;
        }
        __syncthreads();
#pragma unroll
        for (int i = 0; i < 2; ++i) {
            int idx = i * 256 + t;
            int n = idx >> 3, kc = (idx & 7) * 8;
            bf16 tmp[8];
#pragma unroll
            for (int j = 0; j < 8; ++j) tmp[j] = tile[(kc + j) * 72 + n];
            *(uint4*)(Wt + (n0 + n) * EE + k0 + kc) = *(uint4*)tmp;
        }
    } else {
        const int b = bid - 3072;
        float* xs = (float*)tile;
        if (t < 64) {
            const float xiv = xi[b];
            float xv = 0.f;
            if (t < 32) xv = xiv * w1[t] + b1[t];
            float sm = xv;
            for (int off = 1; off < 32; off <<= 1) sm += __shfl_xor(sm, off);
            const float mu = sm * (1.f / 32.f);
            float dv = (t < 32) ? (xv - mu) : 0.f;
            float s2 = dv * dv;
            for (int off = 1; off < 32; off <<= 1) s2 += __shfl_xor(s2, off);
            const float var = s2 * (1.f / 32.f);
            if (t < 32) {
                float xn = (xv - mu) * rsqrtf(var + 1e-5f) * lng[t] + lnb[t];
                float ge = 0.5f * xn * (1.f + erff(xn * 0.70710678118654752f));
                xs[t] = ge;
            }
        }
        __syncthreads();
        if (t < 64) {
            float acc = b2[t];
            for (int j = 0; j < 32; ++j) acc += xs[j] * w2[j * DD + t];
            for (int h = 0; h < HH; ++h) {
                float sg = 1.f / (1.f + __expf(-gate[h]));
                adapt[(b * HH + h) * DD + t] = 1.f + sg * acc;
            }
        }
    }
}

// ---------------------------------------------------------------------------
// Kernel 2: QKV GEMM — 128x128 tile, BK=32, dbuf DMA, one barrier/iter.
// q-scale folds 0.125*log2(e) so attention uses bare v_exp_f32 (exp2).
// K and V^T outputs in PERMUTED TILE LAYOUT (R4):
//   idx = bh*131072 + kt*4096 + mf*2048 + c*512 + lane*8 + j
// Epilogue v2 (R5, verified): scaled results -> XOR-swizzled LDS tile ->
// 8 x dwordx4 stores/thread.  bias/adapt hoisted to per-column FMA factors.
// ---------------------------------------------------------------------------
__global__ __launch_bounds__(256, 3) void gemm_qkv(
    const bf16* __restrict__ Aq, const bf16* __restrict__ Bqk,
    const bf16* __restrict__ Av,
    const float* __restrict__ bias, const float* __restrict__ bias2,
    const float* __restrict__ bias3, const float* __restrict__ adapt,
    bf16* __restrict__ outqk, bf16* __restrict__ outvt) {
    __shared__ bf16 sh[16384];  // main loop: As/Bs; epilogue: 128x128 tile
    bf16* As = sh;
    bf16* Bs = sh + 8192;

    const int t = threadIdx.x;
    const int w = t >> 6, lane = t & 63;
    const int mrow = lane & 15, quad = lane >> 4;
    const int wm = (w & 1) * 64, wn = (w >> 1) * 64;

    int md, bx, by;
    const bf16 *Ap, *Bp;
    int bid = blockIdx.x;
    if (bid < 512) { md = 5; bx = bid & 31; by = bid >> 5; Ap = Aq; Bp = Bqk; }
    else { md = 4; bid -= 512; bx = bid & 7; by = bid >> 3; Ap = Av; Bp = Aq; }
    const int m0 = bx * 128, n0 = by * 128;
    const int m2 = (md == 5) ? (by >> 3) : 0;  // 0=Q, 1=K (block-uniform)

    f32x4 acc[4][4];
#pragma unroll
    for (int i = 0; i < 4; ++i)
#pragma unroll
        for (int j = 0; j < 4; ++j) acc[i][j] = zero4();

    const int dr = lane >> 2;
    const int dcg = ((lane & 3) ^ (dr & 3)) * 8;
    const bf16* Ag = Ap + (size_t)(m0 + w * 16 + dr) * EE + dcg;
    const bf16* Bg = Bp + (size_t)(n0 + w * 16 + dr) * EE + dcg;
    bf16* Al = As + (w * 16) * 32;
    bf16* Bl = Bs + (w * 16) * 32;

    gload16(Ag, Al);
    gload16(Ag + 64 * EE, Al + 64 * 32);
    gload16(Bg, Bl);
    gload16(Bg + 64 * EE, Bl + 64 * 32);

    for (int kt = 0; kt < 32; ++kt) {
        __syncthreads();
        if (kt < 31) {
            const int kn = (kt + 1) * 32;
            const int nb = (kt + 1) & 1;
            gload16(Ag + kn, Al + nb * 4096);
            gload16(Ag + 64 * EE + kn, Al + nb * 4096 + 64 * 32);
            gload16(Bg + kn, Bl + nb * 4096);
            gload16(Bg + 64 * EE + kn, Bl + nb * 4096 + 64 * 32);
        }
        const bf16* Ab = As + (kt & 1) * 4096;
        const bf16* Bb = Bs + (kt & 1) * 4096;
        const int sw = (quad ^ (mrow & 3)) * 8;
        bf16x8 af[4], bfr[4];
#pragma unroll
        for (int i = 0; i < 4; ++i)
            af[i] = *(const bf16x8*)(Ab + (wm + i * 16 + mrow) * 32 + sw);
#pragma unroll
        for (int j = 0; j < 4; ++j)
            bfr[j] = *(const bf16x8*)(Bb + (wn + j * 16 + mrow) * 32 + sw);
#pragma unroll
        for (int i = 0; i < 4; ++i)
#pragma unroll
            for (int j = 0; j < 4; ++j)
                acc[i][j] = MFMA16(af[i], bfr[j], acc[i][j]);
    }

    // ---- epilogue v2: scale -> swizzled LDS -> vectorized stores ----
    __syncthreads();  // staging LDS now dead; safe to overwrite

    if (md == 5) {
        const int bq_ = m0 >> 11;
        float cmul[4], cadd[4];
#pragma unroll
        for (int j = 0; j < 4; ++j) {
            const int cl = (n0 & 1023) + wn + j * 16 + mrow;
            const int hh = cl >> 6, dd2 = cl & 63;
            const float ad = adapt[(bq_ * HH + hh) * DD + dd2];
            const float sc = m2 ? 1.f : 0.18033688011113811f;
            cmul[j] = ad * sc;
            cadd[j] = (m2 ? bias2[cl] : bias[cl]) * ad * sc;
        }
#pragma unroll
        for (int i = 0; i < 4; ++i)
#pragma unroll
            for (int j = 0; j < 4; ++j) {
                const int lcol = wn + j * 16 + mrow;
#pragma unroll
                for (int r = 0; r < 4; ++r) {
                    const int lrow = wm + i * 16 + quad * 4 + r;
                    const float v = acc[i][j][r] * cmul[j] + cadd[j];
                    *(bf16*)((char*)sh + lrow * 256 +
                             ((lcol * 2) ^ ((lrow & 15) << 4))) = (bf16)v;
                }
            }
    } else {
        float radd[16];
#pragma unroll
        for (int i = 0; i < 4; ++i)
#pragma unroll
            for (int r = 0; r < 4; ++r)
                radd[i * 4 + r] = bias3[m0 + wm + i * 16 + quad * 4 + r];
#pragma unroll
        for (int i = 0; i < 4; ++i)
#pragma unroll
            for (int j = 0; j < 4; ++j) {
                const int lcol = wn + j * 16 + mrow;
#pragma unroll
                for (int r = 0; r < 4; ++r) {
                    const int lrow = wm + i * 16 + quad * 4 + r;
                    const float v = acc[i][j][r] + radd[i * 4 + r];
                    *(bf16*)((char*)sh + lrow * 256 +
                             ((lcol * 2) ^ ((lrow & 15) << 4))) = (bf16)v;
                }
            }
    }
    __syncthreads();

#pragma unroll
    for (int p = 0; p < 8; ++p) {
        const int lrow = p * 16 + (t >> 4);
        const int lcol0 = (t & 15) * 8;
        bf16x8 val = *(const bf16x8*)((const char*)sh + lrow * 256 +
                                      ((lcol0 * 2) ^ ((lrow & 15) << 4)));
        if (md == 5) {
            const int bq_ = m0 >> 11;
            const int s_ = (m0 + lrow) & (SS - 1);
            const int cl = (n0 & 1023) + lcol0;
            const int hh = cl >> 6, d0 = cl & 63;
            if (!m2) {
                *(bf16x8*)(outqk + ((size_t)(bq_ * HH + hh) * SS + s_) * DD + d0) = val;
            } else {
                const size_t base = (size_t)MM * EE + (size_t)(bq_ * HH + hh) * 131072;
                const int a2 = (s_ >> 6) * 4096 + ((s_ >> 5) & 1) * 2048 +
                               (d0 >> 4) * 512 +
                               ((s_ & 31) + ((d0 >> 3) & 1) * 32) * 8;
                *(bf16x8*)(outqk + base + a2) = val;
            }
        } else {
            const int rowv = m0 + lrow;
            const int hv = rowv >> 6, dv = rowv & 63;
            const int colv = n0 + lcol0;
            const int bv_ = colv >> 11, sv = colv & (SS - 1);
            const size_t base = (size_t)(bv_ * HH + hv) * 131072;
            const int a2 = (sv >> 6) * 4096 + (dv >> 5) * 2048 +
                           ((sv >> 4) & 3) * 512 +
                           ((dv & 31) + ((sv >> 3) & 1) * 32) * 8;
            *(bf16x8*)(outvt + base + a2) = val;
        }
    }
}

// ---------------------------------------------------------------------------
// Kernel 3: final GEMM (R5 epilogue v2, verified).
// ---------------------------------------------------------------------------
__global__ __launch_bounds__(256, 3) void gemm_o(
    const bf16* __restrict__ A, const bf16* __restrict__ Bt,
    const float* __restrict__ bias, float* __restrict__ outf) {
    __shared__ bf16 As[2 * 128 * 64];  // 32KB; epilogue reuses as 128x64 f32
    __shared__ bf16 Bs[2 * 64 * 64];

    const int t = threadIdx.x;
    const int w = t >> 6, lane = t & 63;
    const int mrow = lane & 15, quad = lane >> 4;
    const int m0 = blockIdx.x * 128, n0 = blockIdx.y * 64;

    f32x4 acc[2][4];
#pragma unroll
    for (int i = 0; i < 2; ++i)
#pragma unroll
        for (int j = 0; j < 4; ++j) acc[i][j] = zero4();

    const int grow = lane >> 3;
    const int gsw = ((lane & 7) ^ grow) * 8;
    const bf16* Ag = A + (size_t)(m0 + w * 32 + grow) * EE + gsw;
    const bf16* Bg = Bt + (size_t)(n0 + w * 16 + grow) * EE + gsw;
    bf16* Al = As + (w * 32) * 64;
    bf16* Bl = Bs + (w * 16) * 64;

#pragma unroll
    for (int i = 0; i < 4; ++i) gload16(Ag + i * 8 * EE, Al + i * 8 * 64);
#pragma unroll
    for (int i = 0; i < 2; ++i) gload16(Bg + i * 8 * EE, Bl + i * 8 * 64);

    for (int kt = 0; kt < 16; ++kt) {
        __syncthreads();
        if (kt < 15) {
            const int kn = (kt + 1) * 64;
            const int nb = (kt + 1) & 1;
#pragma unroll
            for (int i = 0; i < 4; ++i)
                gload16(Ag + i * 8 * EE + kn, Al + nb * 8192 + i * 8 * 64);
#pragma unroll
            for (int i = 0; i < 2; ++i)
                gload16(Bg + i * 8 * EE + kn, Bl + nb * 4096 + i * 8 * 64);
        }
        const bf16* Ab = As + (kt & 1) * 8192;
        const bf16* Bb = Bs + (kt & 1) * 4096;
#pragma unroll
        for (int ks = 0; ks < 2; ++ks) {
            const int cg = ks * 4 + quad;
            const int sw = (cg ^ (mrow & 7)) * 8;
            bf16x8 af[2], bfr[4];
#pragma unroll
            for (int mi = 0; mi < 2; ++mi)
                af[mi] = *(const bf16x8*)(Ab + (w * 32 + mi * 16 + mrow) * 64 + sw);
#pragma unroll
            for (int nj = 0; nj < 4; ++nj)
                bfr[nj] = *(const bf16x8*)(Bb + (nj * 16 + mrow) * 64 + sw);
#pragma unroll
            for (int mi = 0; mi < 2; ++mi)
#pragma unroll
                for (int nj = 0; nj < 4; ++nj)
                    acc[mi][nj] = MFMA16(af[mi], bfr[nj], acc[mi][nj]);
        }
    }

    // ---- epilogue v2 ----
    __syncthreads();  // staging LDS dead
    char* fs = (char*)As;  // 128 rows x 256B (64 f32), swizzled
    float cadd[4];
#pragma unroll
    for (int nj = 0; nj < 4; ++nj) cadd[nj] = bias[n0 + nj * 16 + mrow];
#pragma unroll
    for (int mi = 0; mi < 2; ++mi)
#pragma unroll
        for (int nj = 0; nj < 4; ++nj) {
            const int lcol = nj * 16 + mrow;
#pragma unroll
            for (int r = 0; r < 4; ++r) {
                const int lrow = w * 32 + mi * 16 + quad * 4 + r;
                *(float*)(fs + lrow * 256 + ((lcol * 4) ^ ((lrow & 15) << 4))) =
                    acc[mi][nj][r] + cadd[nj];
            }
        }
    __syncthreads();

#pragma unroll
    for (int p = 0; p < 8; ++p) {
        const int lrow = p * 16 + (t >> 4);
        const int lcol0 = (t & 15) * 4;
        float4 val = *(const float4*)(fs + lrow * 256 +
                                      ((lcol0 * 4) ^ ((lrow & 15) << 4)));
        *(float4*)(outf + (size_t)(m0 + lrow) * EE + n0 + lcol0) = val;
    }
}

// ---------------------------------------------------------------------------
// Kernel 4: flash attention — R8: P32-LEVEL SOFTWARE PIPELINE + permlane.
// R6 post-mortem: st-level pipeline (+32 f32 via by-ref array swap) spilled
// (WRITE 8->79MB) — function-boundary killed SROA.  R7: s_barrier clustering
// hurt (54->59us).  R8: pipeline at the PACKED level instead: keep pb(t-1)
// (16 u32) + vf(t-1); each iter issues QK(t)+PV(t-1) as ONE 16-MFMA cluster
// of 4 independent chains (st0,st1,oacc0,oacc1 — 4-deep at 4x spacing), then
// softmax(t) runs with QK(t) already ~16 issues old.  No functions; macro
// with statically-named A/B register sets (rule #20).  Redistribution via
// v_permlane32_swap_b32 (2 instrs/c vs 2 shfl + 6 selects).
// Dead ends: split-K (nondet), K-tile 32/128, LDS staging (R1-R3 61us
// lockstep invariant), st-level reg pipeline via by-ref arrays (R6 spill),
// s_barrier clustering (R7 −8%), grid reshaping (R2/R3 invariant).
// Spill tripwire: VGPR<=128 + WRITE_SIZE >> 8MB  => revert to R5+permlane.
// ---------------------------------------------------------------------------
#define ATTN_SMPACK(ST0, ST1, PBN)                                           \
    do {                                                                     \
        u32 P32_[2][8];                                                      \
        _Pragma("unroll")                                                    \
        for (int rp = 0; rp < 8; ++rp) {                                     \
            float pa_ = __builtin_amdgcn_exp2f((ST0)[2 * rp]);               \
            float pb_ = __builtin_amdgcn_exp2f((ST0)[2 * rp + 1]);           \
            ls[rp & 3] += pa_ + pb_;                                         \
            P32_[0][rp] = pkbf(pa_, pb_);                                    \
            float pc_ = __builtin_amdgcn_exp2f((ST1)[2 * rp]);               \
            float pd_ = __builtin_amdgcn_exp2f((ST1)[2 * rp + 1]);           \
            ls[rp & 3] += pc_ + pd_;                                         \
            P32_[1][rp] = pkbf(pc_, pd_);                                    \
        }                                                                    \
        _Pragma("unroll")                                                    \
        for (int c = 0; c < 4; ++c) {                                        \
            const int mfs_ = c >> 1, ro_ = (c & 1) * 4;                      \
            u32 a0_ = P32_[mfs_][ro_ + 0], a1_ = P32_[mfs_][ro_ + 1];        \
            u32 b0_ = P32_[mfs_][ro_ + 2], b1_ = P32_[mfs_][ro_ + 3];        \
            PSWAP(a0_, b0_); PSWAP(a1_, b1_);                                \
            PBN[c * 4 + 0] = a0_; PBN[c * 4 + 1] = a1_;                      \
            PBN[c * 4 + 2] = b0_; PBN[c * 4 + 3] = b1_;                      \
        }                                                                    \
    } while (0)

// tile T: load V(T)->VFN, cluster {QK(T) w/ KU, PV(T-1) w/ VFP,PBP},
// prefetch K(T+2)->KU, softmax(T)->PBN.
#define ATTN_STEP(T, KU, VFP, VFN, PBP, PBN, DOPF)                           \
    do {                                                                     \
        _Pragma("unroll")                                                    \
        for (int mf = 0; mf < 2; ++mf)                                       \
            _Pragma("unroll")                                                \
            for (int c = 0; c < 4; ++c)                                      \
                VFN[mf * 4 + c] = *(const bf16x8*)(vbase + (T) * 4096 +      \
                                                   mf * 2048 + c * 512);     \
        f32x16 st0, st1;                                                     \
        _Pragma("unroll")                                                    \
        for (int i = 0; i < 16; ++i) { st0[i] = 0.f; st1[i] = 0.f; }         \
        __builtin_amdgcn_s_setprio(1);                                       \
        _Pragma("unroll")                                                    \
        for (int c = 0; c < 4; ++c) {                                        \
            st0 = MFMA32(KU[c], qf[c], st0);                                 \
            st1 = MFMA32(KU[4 + c], qf[c], st1);                             \
            union { u32 u[4]; bf16x8 v; } pv_;                               \
            pv_.u[0] = PBP[c * 4 + 0]; pv_.u[1] = PBP[c * 4 + 1];            \
            pv_.u[2] = PBP[c * 4 + 2]; pv_.u[3] = PBP[c * 4 + 3];            \
            oacc[0] = MFMA32(VFP[c], pv_.v, oacc[0]);                        \
            oacc[1] = MFMA32(VFP[4 + c], pv_.v, oacc[1]);                    \
        }                                                                    \
        __builtin_amdgcn_s_setprio(0);                                       \
        if (DOPF) {                                                          \
            const int ktp_ = ((T) + 2 < NT) ? (T) + 2 : NT - 1;              \
            _Pragma("unroll")                                                \
            for (int mf = 0; mf < 2; ++mf)                                   \
                _Pragma("unroll")                                            \
                for (int c = 0; c < 4; ++c)                                  \
                    KU[mf * 4 + c] = *(const bf16x8*)(kbase + ktp_ * 4096 +  \
                                                      mf * 2048 + c * 512);  \
        }                                                                    \
        ATTN_SMPACK(st0, st1, PBN);                                          \
    } while (0)

__global__ __launch_bounds__(256, 2) void attn_kernel(
    const bf16* __restrict__ q, const bf16* __restrict__ k,
    const bf16* __restrict__ vt, bf16* __restrict__ o0) {
    __shared__ bf16 lds[4 * 2112];  // epilogue transpose only (wave-private)

    const int t = threadIdx.x;
    const int w = t >> 6, lane = t & 63;
    const int q32 = lane & 31, h = lane >> 5;
    const int bh = blockIdx.x & 31;   // same-bh blocks share an XCD
    const int qb = blockIdx.x >> 5;   // 0..15 (128-row q tiles)
    const int qr0 = qb * 128 + w * 32;

    bf16x8 qf[4];
#pragma unroll
    for (int c = 0; c < 4; ++c)
        qf[c] = *(const bf16x8*)(q + (size_t)(bh * SS + qr0 + q32) * DD + c * 16 + h * 8);

    const bf16* kbase = k + (size_t)bh * 131072 + lane * 8;
    const bf16* vbase = vt + (size_t)bh * 131072 + lane * 8;

    f32x16 oacc[2];
#pragma unroll
    for (int i = 0; i < 16; ++i) { oacc[0][i] = 0.f; oacc[1][i] = 0.f; }
    float ls[4] = {0.f, 0.f, 0.f, 0.f};

    bf16x8 Ka[8], Kb[8], vfA[8], vfB[8];
    u32 pbA[16], pbB[16];

    // prologue: K(0)->Ka, K(1)->Kb, V(0)->vfA
#pragma unroll
    for (int mf = 0; mf < 2; ++mf)
#pragma unroll
        for (int c = 0; c < 4; ++c) {
            Ka[mf * 4 + c] = *(const bf16x8*)(kbase + mf * 2048 + c * 512);
            Kb[mf * 4 + c] = *(const bf16x8*)(kbase + 4096 + mf * 2048 + c * 512);
            vfA[mf * 4 + c] = *(const bf16x8*)(vbase + mf * 2048 + c * 512);
        }

    // QK(0) -> softmax -> pbA; then K(2)->Ka (Ka dead after QK(0))
    {
        f32x16 st0, st1;
#pragma unroll
        for (int i = 0; i < 16; ++i) { st0[i] = 0.f; st1[i] = 0.f; }
        __builtin_amdgcn_s_setprio(1);
#pragma unroll
        for (int c = 0; c < 4; ++c) {
            st0 = MFMA32(Ka[c], qf[c], st0);
            st1 = MFMA32(Ka[4 + c], qf[c], st1);
        }
        __builtin_amdgcn_s_setprio(0);
#pragma unroll
        for (int mf = 0; mf < 2; ++mf)
#pragma unroll
            for (int c = 0; c < 4; ++c)
                Ka[mf * 4 + c] = *(const bf16x8*)(kbase + 2 * 4096 + mf * 2048 + c * 512);
        ATTN_SMPACK(st0, st1, pbA);
    }

    // pipeline: t = 1..30 (15 x 2 steps), then t = 31
    for (int i = 0; i < 15; ++i) {
        ATTN_STEP(2 * i + 1, Kb, vfA, vfB, pbA, pbB, 1);
        ATTN_STEP(2 * i + 2, Ka, vfB, vfA, pbB, pbA, 1);
    }
    ATTN_STEP(31, Kb, vfA, vfB, pbA, pbB, 0);

    // drain: PV(31) from vfB, pbB
    __builtin_amdgcn_s_setprio(1);
#pragma unroll
    for (int c = 0; c < 4; ++c) {
        union { u32 u[4]; bf16x8 v; } pv_;
        pv_.u[0] = pbB[c * 4 + 0]; pv_.u[1] = pbB[c * 4 + 1];
        pv_.u[2] = pbB[c * 4 + 2]; pv_.u[3] = pbB[c * 4 + 3];
        oacc[0] = MFMA32(vfB[c], pv_.v, oacc[0]);
        oacc[1] = MFMA32(vfB[4 + c], pv_.v, oacc[1]);
    }
    __builtin_amdgcn_s_setprio(0);

    float lsum = (ls[0] + ls[1]) + (ls[2] + ls[3]);
    lsum += __shfl_xor(lsum, 32);
    const float inv = 1.f / lsum;

    bf16* ob = lds + w * 2112;  // 32 rows x stride 66, wave-private
#pragma unroll
    for (int mf = 0; mf < 2; ++mf)
#pragma unroll
        for (int rp = 0; rp < 8; ++rp) {
            const int d = 32 * mf + 2 * (rp & 1) + 8 * (rp >> 1) + 4 * h;
            *(u32*)(ob + q32 * 66 + d) =
                pkbf(oacc[mf][2 * rp] * inv, oacc[mf][2 * rp + 1] * inv);
        }
    __syncthreads();

    const int b = bh >> 4, head = bh & 15;
    const int half = lane & 1;
    const int r = lane >> 1;
#pragma unroll
    for (int i = 0; i < 4; ++i) {
        bf16x8 val = *(const bf16x8*)(ob + r * 66 + half * 32 + i * 8);
        *(bf16x8*)(o0 + (size_t)(b * SS + qr0 + r) * EE + head * DD +
                   half * 32 + i * 8) = val;
    }
}

// ---------------------------------------------------------------------------
// Single scratch layout, everything in d_ws (40 MiB).  d_out written exactly
// once, by gemm_o.
// ---------------------------------------------------------------------------
extern "C" void kernel_launch(void* const* d_in, const int* in_sizes, int n_in,
                              void* d_out, int out_size, void* d_ws, size_t ws_size,
                              hipStream_t stream) {
    const float* query = (const float*)d_in[0];
    const float* xi    = (const float*)d_in[1];
    const float* Wq = (const float*)d_in[2];  const float* bq = (const float*)d_in[3];
    const float* Wk = (const float*)d_in[4];  const float* bk = (const float*)d_in[5];
    const float* Wv = (const float*)d_in[6];  const float* bv = (const float*)d_in[7];
    const float* Wo = (const float*)d_in[8];  const float* bo = (const float*)d_in[9];
    const float* ew1 = (const float*)d_in[10]; const float* eb1 = (const float*)d_in[11];
    const float* lng = (const float*)d_in[12]; const float* lnb = (const float*)d_in[13];
    const float* ew2 = (const float*)d_in[14]; const float* eb2 = (const float*)d_in[15];
    const float* gate = (const float*)d_in[16];
    float* out = (float*)d_out;

    char* ws = (char*)d_ws;
    const size_t SZ = (size_t)MM * EE * sizeof(bf16);   // 8 MB
    const size_t WSZ = (size_t)EE * EE * sizeof(bf16);  // 2 MB per transposed weight

    bf16* queryc = (bf16*)(ws);            // dead after gemm_qkv
    bf16* p0     = (bf16*)(ws);            // attn output overlays queryc
    bf16* qws    = (bf16*)(ws + SZ);
    bf16* kws    = (bf16*)(ws + 2 * SZ);
    bf16* vtws   = (bf16*)(ws + 3 * SZ);
    bf16* wqT    = (bf16*)(ws + 4 * SZ);
    bf16* wkT    = (bf16*)(ws + 4 * SZ + WSZ);
    bf16* wvT    = (bf16*)(ws + 4 * SZ + 2 * WSZ);
    bf16* woT    = (bf16*)(ws + 4 * SZ + 3 * WSZ);
    float* adaptws = (float*)(ws + 4 * SZ + 4 * WSZ);

    prep_kernel<<<3074, 256, 0, stream>>>(query, queryc, Wq, Wk, Wv, Wo,
                                          wqT, wkT, wvT, woT,
                                          xi, ew1, eb1, lng, lnb, ew2, eb2, gate,
                                          adaptws);

    // combined QK (512) + V^T (256) = 768 blocks = 3/CU
    gemm_qkv<<<768, 256, 0, stream>>>(queryc, wqT, wvT, bq, bk, bv, adaptws,
                                      qws, vtws);

    // 32 bh x 16 q-tiles = 512 blocks of 256 threads (full K-range per block)
    attn_kernel<<<512, 256, 0, stream>>>(qws, kws, vtws, p0);

    gemm_o<<<dim3(MM / 128, EE / 64), 256, 0, stream>>>(p0, woT, bo, out);
}